// Round 20
// baseline (311.381 us; speedup 1.0000x reference)
//
#include <hip/hip_runtime.h>

typedef _Float16 f16;
typedef __fp16 h16x2 __attribute__((ext_vector_type(2)));
typedef f16 f16x8 __attribute__((ext_vector_type(8)));
typedef float f32x4 __attribute__((ext_vector_type(4)));

#define HW    128
#define NPIX  16384      // 128*128
#define CDIM  256
#define DLOI  128
#define LROWS 40000      // B*L
#define DFC   1024
#define KP1   1088       // z / W1t row stride (17*64); cols 1032..1087 zero

// ---------------- mega prep kernel: fused conv (blocks 0..2047) +
// W1 transpose (1088) + W2 transpose (1024) + out fill (157). One launch;
// cheap memory-bound prep blocks backfill CUs as conv blocks retire.
__device__ __forceinline__ void wtrans_body(
    const float* __restrict__ W, f16* __restrict__ Wt, int K, int ldt,
    int permute, int bx, int by, int tid, float (*t)[33]) {
  const int tx = tid & 31, ty = tid >> 5;
#pragma unroll
  for (int i = 0; i < 4; ++i) {
    int kd = by * 32 + ty + i * 8;
    int ks = (permute && kd < 1024) ? ((kd & 127) * 8 + (kd >> 7)) : kd;
    int n = bx * 32 + tx;
    t[ty + i * 8][tx] = (ks < K) ? W[(size_t)ks * DFC + n] : 0.f;
  }
  __syncthreads();
#pragma unroll
  for (int i = 0; i < 4; ++i) {
    int n = bx * 32 + ty + i * 8;
    int k = by * 32 + tx;
    Wt[(size_t)n * ldt + k] = (f16)t[tx][ty + i * 8];
  }
}

__global__ __launch_bounds__(256, 4) void conv_prep(
    const float* __restrict__ feature, const float* __restrict__ Wfc,
    const float* __restrict__ bfc, f16* __restrict__ x,
    const float* __restrict__ W1, f16* __restrict__ W1t,
    const float* __restrict__ W2, f16* __restrict__ W2t,
    float* __restrict__ out, const float* __restrict__ b3) {
  __shared__ unsigned int t16[64 * 128];     // conv tile, 32 KB
  __shared__ float tt[32][33];               // wtrans tile
  const int tid = threadIdx.x;
  const int bid = blockIdx.x;

  if (bid >= 2048) {
    if (bid < 3136) {        // W1 transpose+permute: 32 x 34 tiles
      const int lo = bid - 2048;
      wtrans_body(W1, W1t, 1032, KP1, 1, lo & 31, lo >> 5, tid, tt);
    } else if (bid < 4160) { // W2 transpose: 32 x 32 tiles
      const int lo = bid - 3136;
      wtrans_body(W2, W2t, 1024, 1024, 0, lo & 31, lo >> 5, tid, tt);
    } else {                 // fill out with b3
      const int i = (bid - 4160) * 256 + tid;
      if (i < LROWS) out[i] = b3[0];
    }
    return;
  }

  // ----- fused transpose+conv1x1
  // LDS swizzle S(pix) = 4*((pix ^ (pix>>2)) & 7): writes conflict-free
  // (old 4*(pix&7) gave only 2 banks per 16-lane store group = 8-way);
  // reads stay exactly-even (lrow^(lrow>>2) covers all 8 values 2x).
  const int l = tid & 63;
  const int w = tid >> 6;                    // wave 0..3 -> 32-d strip
  const int b = bid & 7;                     // batch -> XCD pin
  const int pix0 = (bid >> 3) * 64;
  const int lrow = l & 15, g4 = l >> 4;

  const float* fb = feature + (size_t)b * CDIM * NPIX;

  const int cpb = tid >> 4;                  // 0..15
  const int px4 = (tid & 15) * 4;
#pragma unroll
  for (int pass = 0; pass < 8; ++pass) {
    const int cp = cpb + pass * 16;          // 0..127
    const float* r0 = fb + (size_t)(2 * cp) * NPIX + pix0 + px4;
    float4 a = *(const float4*)r0;
    float4 c = *(const float4*)(r0 + NPIX);
    union { h16x2 h; unsigned int u; } v[4];
    v[0].h = __builtin_amdgcn_cvt_pkrtz(a.x, c.x);
    v[1].h = __builtin_amdgcn_cvt_pkrtz(a.y, c.y);
    v[2].h = __builtin_amdgcn_cvt_pkrtz(a.z, c.z);
    v[3].h = __builtin_amdgcn_cvt_pkrtz(a.w, c.w);
#pragma unroll
    for (int i = 0; i < 4; ++i) {
      const int pix = px4 + i;
      const int sw = ((pix ^ (pix >> 2)) & 7) * 4;
      t16[pix * 128 + (cp ^ sw)] = v[i].u;
    }
  }
  __syncthreads();

  f32x4 acc[4][2] = {};
#pragma unroll
  for (int kf = 0; kf < 8; ++kf) {
    const int kb = kf * 32 + g4 * 8;
    f16x8 bf[2];
#pragma unroll
    for (int n = 0; n < 2; ++n) {
      const float* wp = &Wfc[(size_t)(w * 32 + n * 16 + lrow) * CDIM + kb];
      float4 w0 = *(const float4*)wp;
      float4 w1 = *(const float4*)(wp + 4);
      union { f16x8 v; h16x2 h[4]; } u;
      u.h[0] = __builtin_amdgcn_cvt_pkrtz(w0.x, w0.y);
      u.h[1] = __builtin_amdgcn_cvt_pkrtz(w0.z, w0.w);
      u.h[2] = __builtin_amdgcn_cvt_pkrtz(w1.x, w1.y);
      u.h[3] = __builtin_amdgcn_cvt_pkrtz(w1.z, w1.w);
      bf[n] = u.v;
    }
    const int cp0 = kf * 16 + g4 * 4;
#pragma unroll
    for (int m = 0; m < 4; ++m) {
      const int pix = m * 16 + lrow;
      const int sw = ((pix ^ (pix >> 2)) & 7) * 4;
      const f16x8 af = *(const f16x8*)(t16 + pix * 128 + (cp0 ^ sw));
#pragma unroll
      for (int n = 0; n < 2; ++n)
        acc[m][n] = __builtin_amdgcn_mfma_f32_16x16x32_f16(af, bf[n], acc[m][n], 0, 0, 0);
    }
  }

#pragma unroll
  for (int m = 0; m < 4; ++m) {
#pragma unroll
    for (int r = 0; r < 4; ++r) {
      const int pix = pix0 + m * 16 + g4 * 4 + r;
      f16* xr = x + ((size_t)b * NPIX + pix) * DLOI;
#pragma unroll
      for (int n = 0; n < 2; ++n) {
        const int d = w * 32 + n * 16 + lrow;
        xr[d] = (f16)(acc[m][n][r] + bfc[d]);
      }
    }
  }
}

// ---------------- sampling + bilinear + maxpool(4) + concat -> z[40000][1088] fp16
__global__ __launch_bounds__(256) void sample_kernel(
    const f16* __restrict__ x, const float* __restrict__ p,
    const float* __restrict__ feat, f16* __restrict__ z) {
  const int tid = threadIdx.x;
  const int wv = tid >> 6;
  const int lane = tid & 63;
  const int sub = lane >> 4;           // pool group within half
  const int cl = lane & 15;            // channel block (8 ch)
  const int bid = blockIdx.x;          // 0..9999
  const int b = bid & 7;               // batch -> XCD pin
  const int row = b * 5000 + (bid >> 3) * 4 + wv;

  const float4 pe = *(const float4*)&p[(size_t)row * 4]; // p0x p0y p1x p1y
  const size_t bb = (size_t)b * NPIX;
  f16* zr = z + (size_t)row * KP1;

#pragma unroll
  for (int gh = 0; gh < 2; ++gh) {
    const int g = gh * 4 + sub;        // pool group 0..7
    float acc[8];
#pragma unroll
    for (int ci = 0; ci < 8; ++ci) acc[ci] = -1e30f;
#pragma unroll
    for (int pt = 0; pt < 4; ++pt) {
      const int t = g * 4 + pt;
      const float lam = (float)t * (1.0f / 31.0f);
      const float px = pe.x * lam + pe.z * (1.f - lam) - 0.5f;
      const float py = pe.y * lam + pe.w * (1.f - lam) - 0.5f;
      const float px0 = fminf(fmaxf(floorf(px), 0.f), 127.f);
      const float py0 = fminf(fmaxf(floorf(py), 0.f), 127.f);
      const float px1 = fminf(px0 + 1.f, 127.f);
      const float py1 = fminf(py0 + 1.f, 127.f);
      const int ix0 = (int)px0, iy0 = (int)py0, ix1 = (int)px1, iy1 = (int)py1;
      const float w00 = (px1 - px) * (py1 - py);
      const float w10 = (px - px0) * (py1 - py);
      const float w01 = (px1 - px) * (py - py0);
      const float w11 = (px - px0) * (py - py0);

      const f16* r00 = x + (bb + ix0 * HW + iy0) * DLOI + cl * 8;
      const f16* r10 = x + (bb + ix1 * HW + iy0) * DLOI + cl * 8;
      const f16* r01 = x + (bb + ix0 * HW + iy1) * DLOI + cl * 8;
      const f16* r11 = x + (bb + ix1 * HW + iy1) * DLOI + cl * 8;
      f16x8 a  = *(const f16x8*)r00;
      f16x8 bq = *(const f16x8*)r10;
      f16x8 cq = *(const f16x8*)r01;
      f16x8 dq = *(const f16x8*)r11;
#pragma unroll
      for (int ci = 0; ci < 8; ++ci) {
        float m = w00 * (float)a[ci] + w10 * (float)bq[ci] +
                  w01 * (float)cq[ci] + w11 * (float)dq[ci];
        acc[ci] = fmaxf(acc[ci], m);
      }
    }
    f16x8 o;
#pragma unroll
    for (int ci = 0; ci < 8; ++ci) o[ci] = (f16)acc[ci];
    *(f16x8*)(zr + g * 128 + cl * 8) = o;
  }
  if (lane < 8) zr[1024 + lane] = (f16)feat[(size_t)row * 8 + lane];
  else if (lane < 36) *(unsigned int*)((char*)zr + 2064 + (lane - 8) * 4) = 0u;
}

// ================= 256x128-tile GEMM main loop, 8 waves (512 thr).
// FROZEN (r12): conflict-free 16x16x32, 2-barrier K-loop, 48KB LDS,
// 3 blocks/CU, ~900 TF (2-barrier-family ceiling). 128B-aligned strides only
// (r18 lesson: unaligned A-row stride costs ~10% via split cache lines).
#define GEMM_MAIN_LOOP(A_, Bt_, M_, ksteps_, lda_)                              \
  __shared__ f16 As[256 * 64];                                                  \
  __shared__ f16 Bs[128 * 64];                                                  \
  const int tid = threadIdx.x;                                                  \
  const int l = tid & 63;                                                       \
  const int w = tid >> 6;                                                       \
  const int nwg = gridDim.x;            /* 1256 = 8*157 */                      \
  const int s = (blockIdx.x & 7) * (nwg >> 3) + (blockIdx.x >> 3);              \
  const int m0 = (s >> 3) * 256;                                                \
  const int n0 = (s & 7) * 128;                                                 \
  const int wr = (w >> 1) * 64, wc = (w & 1) * 64;                              \
  const int srow = tid >> 3;            /* 0..63 */                             \
  const int slot = tid & 7;                                                     \
  const int lrow = l & 15, g4 = l >> 4;                                         \
  f32x4 acc[4][4] = {};                                                         \
  for (int kt = 0; kt < ksteps_; ++kt) {                                        \
    const int kb = kt * 64;                                                     \
    __syncthreads();                                                            \
    _Pragma("unroll")                                                           \
    for (int c = 0; c < 4; ++c) {                                               \
      int row = c * 64 + srow;                                                  \
      int arow = m0 + row; if (arow >= M_) arow = M_ - 1;                       \
      const f16* g = A_ + (size_t)arow * lda_ + kb + ((slot ^ (row & 7)) * 8);  \
      __builtin_amdgcn_global_load_lds(                                         \
          (const __attribute__((address_space(1))) void*)g,                     \
          (__attribute__((address_space(3))) void*)(As + row * 64 + slot * 8),  \
          16, 0, 0);                                                            \
    }                                                                           \
    _Pragma("unroll")                                                           \
    for (int c = 0; c < 2; ++c) {                                               \
      int row = c * 64 + srow;                                                  \
      const f16* g = Bt_ + (size_t)(n0 + row) * lda_ + kb + ((slot ^ (row & 7)) * 8); \
      __builtin_amdgcn_global_load_lds(                                         \
          (const __attribute__((address_space(1))) void*)g,                     \
          (__attribute__((address_space(3))) void*)(Bs + row * 64 + slot * 8),  \
          16, 0, 0);                                                            \
    }                                                                           \
    __syncthreads();                                                            \
    _Pragma("unroll")                                                           \
    for (int kh = 0; kh < 2; ++kh) {                                            \
      f16x8 af[4], bf[4];                                                       \
      _Pragma("unroll")                                                         \
      for (int m = 0; m < 4; ++m) {                                             \
        int row = wr + m * 16 + lrow;                                           \
        int sl = (g4 + 4 * kh) ^ (row & 7);                                     \
        af[m] = *(const f16x8*)(As + row * 64 + sl * 8);                        \
      }                                                                         \
      _Pragma("unroll")                                                         \
      for (int n = 0; n < 4; ++n) {                                             \
        int row = wc + n * 16 + lrow;                                           \
        int sl = (g4 + 4 * kh) ^ (row & 7);                                     \
        bf[n] = *(const f16x8*)(Bs + row * 64 + sl * 8);                        \
      }                                                                         \
      _Pragma("unroll")                                                         \
      for (int m = 0; m < 4; ++m)                                               \
        _Pragma("unroll")                                                       \
        for (int n = 0; n < 4; ++n)                                             \
          acc[m][n] = __builtin_amdgcn_mfma_f32_16x16x32_f16(af[m], bf[n], acc[m][n], 0, 0, 0); \
    }                                                                           \
  }

// ---------------- GEMM1: C = relu_f16(A @ Bt^T + bias), h1 output
__global__ __launch_bounds__(512, 4) void gemm_f16(
    const f16* __restrict__ A, const f16* __restrict__ Bt,
    const float* __restrict__ bias, f16* __restrict__ C,
    int M, int ksteps, int lda) {
  GEMM_MAIN_LOOP(A, Bt, M, ksteps, lda)

  const int ocol0 = n0 + wc + lrow;
  const int orow0 = m0 + wr + g4 * 4;
#pragma unroll
  for (int m = 0; m < 4; ++m) {
#pragma unroll
    for (int r = 0; r < 4; ++r) {
      int orow = orow0 + m * 16 + r;
      if (orow >= M) continue;
      f16* crow = C + (size_t)orow * DFC;
#pragma unroll
      for (int n = 0; n < 4; ++n) {
        int col = ocol0 + n * 16;
        float v = acc[m][n][r] + bias[col];
        crow[col] = (f16)fmaxf(v, 0.f);
      }
    }
  }
}

// ---------------- GEMM2 with fused fc3: out[m] += sum_col relu(h2)*W3[col]
__global__ __launch_bounds__(512, 4) void gemm2_fc3(
    const f16* __restrict__ A, const f16* __restrict__ Bt,
    const float* __restrict__ bias, const float* __restrict__ W3,
    float* __restrict__ out, int M, int ksteps, int lda) {
  GEMM_MAIN_LOOP(A, Bt, M, ksteps, lda)

  const int ocol0 = n0 + wc + lrow;
  const int orow0 = m0 + wr + g4 * 4;
  float b4[4], w3v[4];
#pragma unroll
  for (int n = 0; n < 4; ++n) {
    b4[n] = bias[ocol0 + n * 16];
    w3v[n] = W3[ocol0 + n * 16];
  }
#pragma unroll
  for (int m = 0; m < 4; ++m) {
#pragma unroll
    for (int r = 0; r < 4; ++r) {
      float sacc = 0.f;
#pragma unroll
      for (int n = 0; n < 4; ++n) {
        float v = fmaxf(acc[m][n][r] + b4[n], 0.f);
        sacc += v * w3v[n];
      }
      sacc += __shfl_xor(sacc, 1);
      sacc += __shfl_xor(sacc, 2);
      sacc += __shfl_xor(sacc, 4);
      sacc += __shfl_xor(sacc, 8);
      int orow = orow0 + m * 16 + r;
      if (lrow == 0 && orow < M) atomicAdd(&out[orow], sacc);
    }
  }
}

extern "C" void kernel_launch(void* const* d_in, const int* in_sizes, int n_in,
                              void* d_out, int out_size, void* d_ws, size_t ws_size,
                              hipStream_t stream) {
  const float* feature = (const float*)d_in[0];
  const float* p       = (const float*)d_in[1];
  const float* feat    = (const float*)d_in[2];
  const float* W_fc1   = (const float*)d_in[3];
  const float* b_fc1   = (const float*)d_in[4];
  const float* W1      = (const float*)d_in[5];
  const float* b1      = (const float*)d_in[6];
  const float* W2      = (const float*)d_in[7];
  const float* b2      = (const float*)d_in[8];
  const float* W3      = (const float*)d_in[9];
  const float* b3      = (const float*)d_in[10];
  float* out = (float*)d_out;

  char* ws = (char*)d_ws;
  f16* x    = (f16*)(ws + 0);                   //  33,554,432 B
  f16* z    = (f16*)(ws + 33554432ULL);         //  87,040,000 B (40000x1088)
  f16* h1   = (f16*)(ws + 120594432ULL);        //  81,920,000 B (40000x1024)
  f16* W1t  = (f16*)(ws + 202514432ULL);        //   2,228,224 B (1024x1088, zeros k>=1032)
  f16* W2t  = (f16*)(ws + 204742656ULL);        //   2,097,152 B (1024x1024)

  // one wide launch: conv (2048) + W1t (1088) + W2t (1024) + fill (157)
  hipLaunchKernelGGL(conv_prep, dim3(4317), dim3(256), 0, stream,
                     feature, W_fc1, b_fc1, x, W1, W1t, W2, W2t, out, b3);
  hipLaunchKernelGGL(sample_kernel, dim3(10000), dim3(256), 0, stream,
                     x, p, feat, z);
  hipLaunchKernelGGL(gemm_f16, dim3(1256), dim3(512), 0, stream,
                     z, W1t, b1, h1, LROWS, KP1 / 64, KP1);
  hipLaunchKernelGGL(gemm2_fc3, dim3(1256), dim3(512), 0, stream,
                     h1, W2t, b2, W3, out, LROWS, DFC / 64, DFC);
}